// Round 3
// baseline (687.788 us; speedup 1.0000x reference)
//
#include <hip/hip_runtime.h>
#include <hip/hip_bf16.h>
#include <math.h>

#define IN_F    4096
#define OUT_F   4096
#define N_TOK   8192
#define GROUP   128
#define NSTAGE  4
#define NPAIRS  2048   // IN_F/2 pairs per stage
#define QMAXF   15.0

typedef unsigned short u16;
typedef __bf16 bf16x8 __attribute__((ext_vector_type(8)));
typedef float  f32x4  __attribute__((ext_vector_type(4)));

struct alignas(8) U16x4 { u16 x, y, z, w; };

__device__ __forceinline__ u16 f2bf(float f) {
    unsigned u = __float_as_uint(f);
    unsigned r = (u + 0x7fffu + ((u >> 16) & 1u)) >> 16;   // RNE
    return (u16)r;
}

__device__ __forceinline__ void gl_lds16(const void* g, void* l) {
    __builtin_amdgcn_global_load_lds(
        (const __attribute__((address_space(1))) void*)g,
        (__attribute__((address_space(3))) void*)l,
        16, 0, 0);
}

__device__ __forceinline__ void bar() {
    asm volatile("" ::: "memory");
    __builtin_amdgcn_s_barrier();
    asm volatile("" ::: "memory");
}

// ---------------------------------------------------------------- tables ----
__global__ void make_tabs(const float* __restrict__ theta,
                          double* __restrict__ ctab, double* __restrict__ stab) {
    int i = blockIdx.x * 256 + threadIdx.x;
    if (i < NSTAGE * NPAIRS) {
        double t = (double)theta[i];
        ctab[i] = cos(t);
        stab[i] = sin(t);
    }
}

// ------------------------------------------------------------- transform ----
// One WAVE per (row, group): block-diagonal chain in LDS doubles, wave-sync.
__global__ __launch_bounds__(256) void build_w(
    const float* __restrict__ weight, const float* __restrict__ cs,
    const float* __restrict__ qs, const float* __restrict__ qzp,
    const int* __restrict__ pairs,
    const double* __restrict__ ctab, const double* __restrict__ stab,
    u16* __restrict__ wb) {
    __shared__ double gbuf[4][GROUP];
    const int wave = threadIdx.x >> 6, l = threadIdx.x & 63;
    const int task = blockIdx.x * 4 + wave;        // 4096*32 tasks
    const int o = task >> 5, g = task & 31;
    double* gb = gbuf[wave];
    const int e0 = g * GROUP;

    float2 wv = *(const float2*)(weight + (size_t)o * IN_F + e0 + 2 * l);
    float2 cv = *(const float2*)(cs + e0 + 2 * l);
    gb[2 * l]     = (double)wv.x * (double)cv.x;
    gb[2 * l + 1] = (double)wv.y * (double)cv.y;
    __builtin_amdgcn_wave_barrier();

    const int2* prs = (const int2*)pairs;          // (i,j) pairs, 8B aligned

    for (int r = 0; r < NSTAGE; ++r) {
        int2 p = prs[r * (IN_F / 2) + g * 64 + l];
        double c = ctab[r * NPAIRS + g * 64 + l];
        double s = stab[r * NPAIRS + g * 64 + l];
        double xi = gb[p.x], xj = gb[p.y];
        __builtin_amdgcn_wave_barrier();
        gb[p.x] =  xi * c + xj * s;
        gb[p.y] = -xi * s + xj * c;
        __builtin_amdgcn_wave_barrier();
    }

    {
        double s   = fmin(fmax((double)qs[o * 32 + g], 1e-5), 1e5);
        double rzp = fmin(fmax(-rint((double)qzp[o * 32 + g]), 0.0), QMAXF);
#pragma unroll
        for (int e = 2 * l; e <= 2 * l + 1; ++e) {
            double q = rint(gb[e] / s) + rzp;
            q = fmin(fmax(q, 0.0), QMAXF);
            gb[e] = (q - rzp) * s;
        }
        __builtin_amdgcn_wave_barrier();
    }

    for (int r = NSTAGE - 1; r >= 0; --r) {
        int2 p = prs[r * (IN_F / 2) + g * 64 + l];
        double c = ctab[r * NPAIRS + g * 64 + l];
        double s = stab[r * NPAIRS + g * 64 + l];
        double xi = gb[p.x], xj = gb[p.y];
        __builtin_amdgcn_wave_barrier();
        gb[p.x] = xi * c - xj * s;
        gb[p.y] = xi * s + xj * c;
        __builtin_amdgcn_wave_barrier();
    }

    unsigned lo = f2bf((float)(gb[2 * l]     / (double)cv.x));
    unsigned hi = f2bf((float)(gb[2 * l + 1] / (double)cv.y));
    *(unsigned*)(wb + (size_t)o * IN_F + e0 + 2 * l) = lo | (hi << 16);
}

// ----------------------------------------------------------------- cast x ---
__global__ void cast_x(const float* __restrict__ x, u16* __restrict__ xb) {
    size_t i = ((size_t)blockIdx.x * 256 + threadIdx.x) * 4;
    float4 v = *(const float4*)(x + i);
    U16x4 o;
    o.x = f2bf(v.x); o.y = f2bf(v.y); o.z = f2bf(v.z); o.w = f2bf(v.w);
    *(U16x4*)(xb + i) = o;
}

// ------------------------------------------------------------------ GEMM ----
// C[m,n] = sum_k A[m,k] * B[n,k] + bias[n]   (A: M x K, B: N x K, both bf16)
//
// Faithful m201 port. 256x256 tile, 512 thr / 8 waves (2M x 4N, wave tile
// 128x64), BK=64, 2+2 LDS slots (128 KiB), window = 1 K-tile = 4 phases.
// Quadrant order m0n0 -> m1n0 -> m0n1 -> m1n1: A reads (both ks) finish by
// P2, B n-halves read P1/P3; fragment reuse across phases gives per-phase
// ds_reads 12/8/4/0 (the "12-read phase" of the template). Stages 1
// half-tile/phase: P1/P2 stage B(u+1) (other slot, free; L2-resident, short
// 2-3 phase window), P3/P4 stage A(u+2) (own slot, A reads done at P2;
// HBM stream gets 4-5 phase window). Exactly one counted vmcnt(4) per
// window at P4 -- retires tile u+1 entirely, leaves A(u+2) in flight.
// Never drains to 0 mid-loop (the m97 stall). Raw s_barrier pairs per
// phase; MFMA under setprio(1) (T5 pays on phase-split schedules only).
// LDS chunk-XOR swizzle (chunk ^= row&7) via pre-swizzled global source;
// ds_read_b128 2-way per bank = free (measured 0 conflicts R1/R2).
__global__ __launch_bounds__(512, 2) void gemm_bt(
    const u16* __restrict__ A, const u16* __restrict__ B,
    const float* __restrict__ bias, float* __restrict__ C) {
    constexpr int K = IN_F;
    constexpr int N = OUT_F;
    constexpr int NT = K / 64;                       // 64 K-tiles
    __shared__ __align__(16) u16 As[2][256 * 64];    // 64 KB
    __shared__ __align__(16) u16 Bs[2][256 * 64];    // 64 KB

    const int tid  = threadIdx.x;
    const int wave = tid >> 6, lane = tid & 63;
    const int lrow = lane & 15, lq = lane >> 4;
    const int wm = wave >> 2, wn = wave & 3;         // 2x4 wave grid

    // XCD-bijective swizzle (512 wgs % 8 == 0): each XCD owns 2 nt values
    // -> its 4 MB of B panels stay L2-resident.
    const int wg = (blockIdx.x & 7) * 64 + (blockIdx.x >> 3);
    const int mt = wg & 31, nt = wg >> 5;
    const int m0 = mt * 256, n0 = nt * 256;

    // staging: half-tile = 128 rows x 64 cols x 2B = 16 KB = 2 gl_lds
    // rounds of 512 thr x 16 B. Linear LDS dest; swizzled global chunk.
    const int prow = tid >> 3;                       // 0..63 within round
    const int pch  = (tid & 7) ^ ((tid >> 3) & 7);   // pre-swizzled src chunk
    const u16* pA = A + (size_t)(m0 + prow) * K + pch * 8;
    const u16* pB = B + (size_t)(n0 + prow) * K + pch * 8;

#define STG_A(s, t, h) do {                                                    \
        gl_lds16(pA + (size_t)((h) * 128) * K + (t) * 64,                      \
                 &As[s][(h) * 8192 + (wave << 9)]);                            \
        gl_lds16(pA + (size_t)((h) * 128 + 64) * K + (t) * 64,                 \
                 &As[s][(h) * 8192 + 4096 + (wave << 9)]);                     \
    } while (0)
#define STG_B(s, t, h) do {                                                    \
        gl_lds16(pB + (size_t)((h) * 128) * K + (t) * 64,                      \
                 &Bs[s][(h) * 8192 + (wave << 9)]);                            \
        gl_lds16(pB + (size_t)((h) * 128 + 64) * K + (t) * 64,                 \
                 &Bs[s][(h) * 8192 + 4096 + (wave << 9)]);                     \
    } while (0)

    // fragment reads: row stride 64 u16 (128 B); global chunk (ks*4+lq)
    // lives at LDS chunk (ks*4+lq)^(row&7); row&7 == lrow&7 (all row terms
    // are multiples of 8) so per-(j,ks) deltas fold into ds offsets.
#define RD_A(dst, mih) do {                                                    \
        _Pragma("unroll")                                                      \
        for (int ks_ = 0; ks_ < 2; ++ks_)                                      \
        _Pragma("unroll")                                                      \
        for (int j_ = 0; j_ < 4; ++j_) {                                       \
            const int ar_ = (wm << 7) + ((mih) << 6) + (j_ << 4) + lrow;       \
            dst[ks_ * 4 + j_] = *(const bf16x8*)&as_[(ar_ << 6) +              \
                ((((ks_ << 2) | lq) ^ (ar_ & 7)) << 3)];                       \
        }                                                                      \
    } while (0)
#define RD_B(dst, njh) do {                                                    \
        _Pragma("unroll")                                                      \
        for (int ks_ = 0; ks_ < 2; ++ks_)                                      \
        _Pragma("unroll")                                                      \
        for (int j_ = 0; j_ < 2; ++j_) {                                       \
            const int br_ = (wn << 6) + ((njh) << 5) + (j_ << 4) + lrow;       \
            dst[ks_ * 2 + j_] = *(const bf16x8*)&bs_[(br_ << 6) +              \
                ((((ks_ << 2) | lq) ^ (br_ & 7)) << 3)];                       \
        }                                                                      \
    } while (0)

    // one C-quadrant x K=64: 16 MFMA; same-acc pairs (ks0,ks1) 8 apart.
#define MFQ(am, bn, mih, njh) do {                                             \
        __builtin_amdgcn_s_setprio(1);                                         \
        _Pragma("unroll")                                                      \
        for (int ks_ = 0; ks_ < 2; ++ks_)                                      \
        _Pragma("unroll")                                                      \
        for (int j_ = 0; j_ < 4; ++j_)                                         \
        _Pragma("unroll")                                                      \
        for (int n_ = 0; n_ < 2; ++n_)                                         \
            acc[((mih) << 2) + j_][((njh) << 1) + n_] =                        \
                __builtin_amdgcn_mfma_f32_16x16x32_bf16(                       \
                    am[ks_ * 4 + j_], bn[ks_ * 2 + n_],                        \
                    acc[((mih) << 2) + j_][((njh) << 1) + n_], 0, 0, 0);       \
        __builtin_amdgcn_s_setprio(0);                                         \
    } while (0)

    f32x4 acc[8][4];
#pragma unroll
    for (int i = 0; i < 8; ++i)
#pragma unroll
        for (int j = 0; j < 4; ++j) acc[i][j] = (f32x4){0.f, 0.f, 0.f, 0.f};

    // prologue: tile 0 (4 halves) + A(1) (2 halves) = 12 loads;
    // vmcnt(4) retires tile 0, leaves A(1)h0,h1 in flight (the invariant).
    STG_A(0, 0, 0); STG_A(0, 0, 1); STG_B(0, 0, 0); STG_B(0, 0, 1);
    STG_A(1, 1, 0); STG_A(1, 1, 1);
    asm volatile("s_waitcnt vmcnt(4)" ::: "memory");
    __builtin_amdgcn_s_barrier();
    asm volatile("" ::: "memory");

    for (int u = 0; u < NT; ++u) {
        const u16* as_ = As[u & 1];
        const u16* bs_ = Bs[u & 1];
        bf16x8 a0[8], a1[8], b0[4], b1[4];

        // ---- P1: quadrant (m0,n0); 12 ds_read; stage B(u+1)h0
        RD_A(a0, 0);
        RD_B(b0, 0);
        if (u < NT - 1) STG_B((u + 1) & 1, u + 1, 0);
        bar();
        MFQ(a0, b0, 0, 0);
        bar();

        // ---- P2: quadrant (m1,n0); 8 ds_read; stage B(u+1)h1
        RD_A(a1, 1);
        if (u < NT - 1) STG_B((u + 1) & 1, u + 1, 1);
        bar();
        MFQ(a1, b0, 1, 0);
        bar();

        // ---- P3: quadrant (m0,n1); 4 ds_read; A(u) reads done -> stage
        //      A(u+2)h0 into own slot
        RD_B(b1, 1);
        if (u < NT - 2) STG_A(u & 1, u + 2, 0);
        bar();
        MFQ(a0, b1, 0, 1);
        bar();

        // ---- P4: quadrant (m1,n1); 0 ds_read; stage A(u+2)h1; counted
        //      wait retires tile u+1 exactly, leaves A(u+2) in flight
        if (u < NT - 2) {
            STG_A(u & 1, u + 2, 1);
            asm volatile("s_waitcnt vmcnt(4)" ::: "memory");
        } else if (u == NT - 2) {
            asm volatile("s_waitcnt vmcnt(0)" ::: "memory");
        }
        bar();
        MFQ(a1, b1, 1, 1);
        bar();
    }

#undef STG_A
#undef STG_B
#undef RD_A
#undef RD_B
#undef MFQ

    // epilogue: C/D layout col = lane&15, row = (lane>>4)*4 + reg
#pragma unroll
    for (int mi = 0; mi < 8; ++mi) {
        int rb = m0 + wm * 128 + mi * 16 + lq * 4;
#pragma unroll
        for (int nj = 0; nj < 4; ++nj) {
            int col = n0 + wn * 64 + nj * 16 + lrow;
            float bv = bias[col];
#pragma unroll
            for (int r = 0; r < 4; ++r)
                C[(size_t)(rb + r) * N + col] = acc[mi][nj][r] + bv;
        }
    }
}

// ---------------------------------------------------------------- launch ----
extern "C" void kernel_launch(void* const* d_in, const int* in_sizes, int n_in,
                              void* d_out, int out_size, void* d_ws, size_t ws_size,
                              hipStream_t stream) {
    const float* x    = (const float*)d_in[0];
    const float* w    = (const float*)d_in[1];
    const float* bias = (const float*)d_in[2];
    const float* cs   = (const float*)d_in[3];
    const float* th   = (const float*)d_in[4];
    const float* qs   = (const float*)d_in[5];
    const float* qzp  = (const float*)d_in[6];
    const int*   pr   = (const int*)d_in[7];
    float* out = (float*)d_out;

    char* ws = (char*)d_ws;
    double* ctab = (double*)ws;                                  // 64 KB
    double* stab = (double*)(ws + 65536);                        // 64 KB
    u16*    xb   = (u16*)(ws + 131072);                          // 64 MB
    u16*    wb   = (u16*)(ws + 131072 + (size_t)N_TOK * IN_F * 2);  // 32 MB

    hipLaunchKernelGGL(make_tabs, dim3((NSTAGE * NPAIRS + 255) / 256), dim3(256),
                       0, stream, th, ctab, stab);
    hipLaunchKernelGGL(build_w, dim3(OUT_F * 32 / 4), dim3(256), 0, stream,
                       w, cs, qs, qzp, pr, ctab, stab, wb);
    hipLaunchKernelGGL(cast_x, dim3(N_TOK * IN_F / 4 / 256), dim3(256), 0, stream,
                       x, xb);
    hipLaunchKernelGGL(gemm_bt, dim3((N_TOK / 256) * (OUT_F / 256)), dim3(512),
                       0, stream, xb, wb, bias, out);
}

// Round 4
// 615.186 us; speedup vs baseline: 1.1180x; 1.1180x over previous
//
#include <hip/hip_runtime.h>
#include <hip/hip_bf16.h>
#include <math.h>

#define IN_F    4096
#define OUT_F   4096
#define N_TOK   8192
#define GROUP   128
#define NSTAGE  4
#define NPAIRS  2048   // IN_F/2 pairs per stage
#define QMAXF   15.0
#define ROWS_PW 8      // rows per wave in build_w (amortizes tab/pair loads)

typedef unsigned short u16;
typedef __bf16 bf16x8 __attribute__((ext_vector_type(8)));
typedef float  f32x4  __attribute__((ext_vector_type(4)));

struct alignas(8) U16x4 { u16 x, y, z, w; };

__device__ __forceinline__ u16 f2bf(float f) {
    unsigned u = __float_as_uint(f);
    unsigned r = (u + 0x7fffu + ((u >> 16) & 1u)) >> 16;   // RNE
    return (u16)r;
}

__device__ __forceinline__ void gl_lds16(const void* g, void* l) {
    __builtin_amdgcn_global_load_lds(
        (const __attribute__((address_space(1))) void*)g,
        (__attribute__((address_space(3))) void*)l,
        16, 0, 0);
}

// ---------------------------------------------------------------- tables ----
__global__ void make_tabs(const float* __restrict__ theta,
                          double* __restrict__ ctab, double* __restrict__ stab) {
    int i = blockIdx.x * 256 + threadIdx.x;
    if (i < NSTAGE * NPAIRS) {
        double t = (double)theta[i];
        ctab[i] = cos(t);
        stab[i] = sin(t);
    }
}

// ------------------------------------------------------------- transform ----
// One WAVE per (row-block, group): the whole chain (scale -> 4 rot -> qdq ->
// 4 inv-rot -> unscale) is block-diagonal per 128-elem group; wave-sync LDS
// doubles for fidelity through rint(). ROWS_PW rows per wave: pairs and
// cos/sin tables are ROW-INVARIANT -> cached in registers once per wave
// (8x fewer gather loads), as is 1/channel_scale (2 f64 divides amortized
// over ROWS_PW rows). qdq uses one reciprocal per (row,group) instead of 2
// divides (f64 a*(1/s) vs a/s differ by <=1 ulp f64 -- far below the f32
// rint-boundary distances of the reference, so no quantization flips).
__global__ __launch_bounds__(256) void build_w(
    const float* __restrict__ weight, const float* __restrict__ cs,
    const float* __restrict__ qs, const float* __restrict__ qzp,
    const int* __restrict__ pairs,
    const double* __restrict__ ctab, const double* __restrict__ stab,
    u16* __restrict__ wb) {
    __shared__ double gbuf[4][GROUP];
    const int wave = threadIdx.x >> 6, l = threadIdx.x & 63;
    const int task = blockIdx.x * 4 + wave;    // (4096/ROWS_PW)*32 tasks
    const int ob = task >> 5, g = task & 31;
    const int o0 = ob * ROWS_PW;
    double* gb = gbuf[wave];
    const int e0 = g * GROUP;

    // per-group constants, row-invariant: cache in registers
    const int2* prs = (const int2*)pairs;      // (i,j) pairs, 8B aligned
    int2   pr_[NSTAGE];
    double c_[NSTAGE], s_[NSTAGE];
#pragma unroll
    for (int r = 0; r < NSTAGE; ++r) {
        pr_[r] = prs[r * (IN_F / 2) + g * 64 + l];
        c_[r]  = ctab[r * NPAIRS + g * 64 + l];
        s_[r]  = stab[r * NPAIRS + g * 64 + l];
    }
    float2 cv = *(const float2*)(cs + e0 + 2 * l);
    const double cvx = (double)cv.x, cvy = (double)cv.y;
    const double rcx = 1.0 / cvx, rcy = 1.0 / cvy;

    for (int o = o0; o < o0 + ROWS_PW; ++o) {
        float2 wv = *(const float2*)(weight + (size_t)o * IN_F + e0 + 2 * l);
        gb[2 * l]     = (double)wv.x * cvx;
        gb[2 * l + 1] = (double)wv.y * cvy;
        __builtin_amdgcn_wave_barrier();

        // forward rotation stages
#pragma unroll
        for (int r = 0; r < NSTAGE; ++r) {
            double xi = gb[pr_[r].x], xj = gb[pr_[r].y];
            __builtin_amdgcn_wave_barrier();
            gb[pr_[r].x] =  xi * c_[r] + xj * s_[r];
            gb[pr_[r].y] = -xi * s_[r] + xj * c_[r];
            __builtin_amdgcn_wave_barrier();
        }

        // group quant-dequant
        {
            double sc  = fmin(fmax((double)qs[o * 32 + g], 1e-5), 1e5);
            double rzp = fmin(fmax(-rint((double)qzp[o * 32 + g]), 0.0), QMAXF);
            double inv = 1.0 / sc;
#pragma unroll
            for (int e = 2 * l; e <= 2 * l + 1; ++e) {
                double q = rint(gb[e] * inv) + rzp;
                q = fmin(fmax(q, 0.0), QMAXF);
                gb[e] = (q - rzp) * sc;
            }
            __builtin_amdgcn_wave_barrier();
        }

        // inverse rotation stages
#pragma unroll
        for (int r = NSTAGE - 1; r >= 0; --r) {
            double xi = gb[pr_[r].x], xj = gb[pr_[r].y];
            __builtin_amdgcn_wave_barrier();
            gb[pr_[r].x] = xi * c_[r] - xj * s_[r];
            gb[pr_[r].y] = xi * s_[r] + xj * c_[r];
            __builtin_amdgcn_wave_barrier();
        }

        unsigned lo = f2bf((float)(gb[2 * l]     * rcx));
        unsigned hi = f2bf((float)(gb[2 * l + 1] * rcy));
        *(unsigned*)(wb + (size_t)o * IN_F + e0 + 2 * l) = lo | (hi << 16);
        __builtin_amdgcn_wave_barrier();   // next row's init vs this row's reads
    }
}

// ----------------------------------------------------------------- cast x ---
__global__ void cast_x(const float* __restrict__ x, u16* __restrict__ xb) {
    size_t i = ((size_t)blockIdx.x * 256 + threadIdx.x) * 4;
    float4 v = *(const float4*)(x + i);
    U16x4 o;
    o.x = f2bf(v.x); o.y = f2bf(v.y); o.z = f2bf(v.z); o.w = f2bf(v.w);
    *(U16x4*)(xb + i) = o;
}

// ------------------------------------------------------------------ GEMM ----
// C[m,n] = sum_k A[m,k] * B[n,k] + bias[n]   (A: M x K, B: N x K, both bf16)
//
// R1 known-good structure (measured 299-300 us, MfmaUtil 40.5): 256x256
// tile, 512 thr / 8 waves (2M x 4N, each 128x64), BK=32 sub-tiles in a
// 4-deep LDS ring (128 KiB). Counted-vmcnt pipeline: main loop NEVER drains
// vmcnt to 0 -- each iteration waits vmcnt(8) (retires only loads issued 3
// sub-tiles earlier), raw s_barrier (no compiler vmcnt(0) drain), then
// issues the next slot's 4 global_load_lds. Tail drains 8 -> 4 -> 0.
// LDS chunk-XOR swizzle via pre-swizzled global source (gl_lds writes
// linearly): quarter-wave ds_read_b128 is 2-way per bank = free (m136;
// measured 0 conflicts).
__global__ __launch_bounds__(512, 2) void gemm_bt(
    const u16* __restrict__ A, const u16* __restrict__ B,
    const float* __restrict__ bias, float* __restrict__ C) {
    constexpr int K = IN_F;
    constexpr int N = OUT_F;
    constexpr int NS = K / 32;                       // 128 sub-tiles
    __shared__ __align__(16) u16 As[4][256 * 32];    // 64 KB
    __shared__ __align__(16) u16 Bs[4][256 * 32];    // 64 KB

    const int tid  = threadIdx.x;
    const int wave = tid >> 6, lane = tid & 63;
    const int lrow = lane & 15, lq = lane >> 4;
    const int wm = wave >> 2, wn = wave & 3;         // 2x4 wave grid

    // XCD-bijective swizzle: 512 wgs, 8 XCDs. Each XCD gets one nt-pair
    // (4 MB of B panels -> L2-resident) across all 32 mt.
    const int wg = (blockIdx.x & 7) * 64 + (blockIdx.x >> 3);
    const int mt = wg & 31, nt = wg >> 5;
    const int m0 = mt * 256, n0 = nt * 256;

    // staging: 512 thr x 16B = 8 KB/round = 128 rows; 2 rounds per operand.
    // LDS dest is linear (gl_lds: wave base + lane*16); global src carries
    // the chunk swizzle: LDS chunk lc of row r holds global chunk lc^((r>>1)&3).
    const int srow = tid >> 2;                              // 0..127
    const int gch  = (tid & 3) ^ ((tid >> 3) & 3);          // swizzled source chunk
    const u16* pA0 = A + (size_t)(m0 + srow) * K + gch * 8;
    const u16* pA1 = pA0 + (size_t)128 * K;
    const u16* pB0 = B + (size_t)(n0 + srow) * K + gch * 8;
    const u16* pB1 = pB0 + (size_t)128 * K;

#define STAGE(slot, s) do {                                         \
        const int ko_ = (s) * 32;                                   \
        gl_lds16(pA0 + ko_, &As[slot][wave * 512]);                 \
        gl_lds16(pA1 + ko_, &As[slot][4096 + wave * 512]);          \
        gl_lds16(pB0 + ko_, &Bs[slot][wave * 512]);                 \
        gl_lds16(pB1 + ko_, &Bs[slot][4096 + wave * 512]);          \
    } while (0)

    f32x4 acc[8][4];
#pragma unroll
    for (int i = 0; i < 8; ++i)
#pragma unroll
        for (int j = 0; j < 4; ++j) acc[i][j] = (f32x4){0.f, 0.f, 0.f, 0.f};

    // prologue: fill 3 ring slots (12 loads in flight)
    STAGE(0, 0); STAGE(1, 1); STAGE(2, 2);

    // Per iteration: wait only for sub-tile s (issued 3 iters ago), barrier,
    // read frags, issue sub-tile s+3 into the slot everyone finished reading
    // last iteration (barrier guarantees), MFMA under setprio(1).
#define BODY(s, VMSTR, DO_STAGE) do {                                          \
        asm volatile("s_waitcnt " VMSTR);                                      \
        __builtin_amdgcn_s_barrier();                                          \
        asm volatile("" ::: "memory");                                         \
        const u16* as_ = As[(s) & 3];                                          \
        const u16* bs_ = Bs[(s) & 3];                                          \
        bf16x8 af[8], bf[4];                                                   \
        _Pragma("unroll")                                                      \
        for (int mi = 0; mi < 8; ++mi) {                                       \
            int ar = wm * 128 + mi * 16 + lrow;                                \
            af[mi] = *(const bf16x8*)&as_[ar * 32 +                            \
                                          (((lq ^ (ar >> 1)) & 3) << 3)];      \
        }                                                                      \
        _Pragma("unroll")                                                      \
        for (int nj = 0; nj < 4; ++nj) {                                       \
            int br = wn * 64 + nj * 16 + lrow;                                 \
            bf[nj] = *(const bf16x8*)&bs_[br * 32 +                            \
                                          (((lq ^ (br >> 1)) & 3) << 3)];      \
        }                                                                      \
        if (DO_STAGE) STAGE(((s) + 3) & 3, (s) + 3);                           \
        __builtin_amdgcn_s_setprio(1);                                         \
        _Pragma("unroll")                                                      \
        for (int mi = 0; mi < 8; ++mi)                                         \
            _Pragma("unroll")                                                  \
            for (int nj = 0; nj < 4; ++nj)                                     \
                acc[mi][nj] = __builtin_amdgcn_mfma_f32_16x16x32_bf16(         \
                    af[mi], bf[nj], acc[mi][nj], 0, 0, 0);                     \
        __builtin_amdgcn_s_setprio(0);                                         \
        asm volatile("" ::: "memory");                                         \
    } while (0)

    for (int s = 0; s < NS - 3; ++s)
        BODY(s, "vmcnt(8)", 1);
    // tail: drain 8 -> 4 -> 0
    BODY(NS - 3, "vmcnt(8)", 0);
    BODY(NS - 2, "vmcnt(4)", 0);
    BODY(NS - 1, "vmcnt(0)", 0);

#undef BODY
#undef STAGE

    // epilogue: C/D layout col = lane&15, row = (lane>>4)*4 + reg
#pragma unroll
    for (int mi = 0; mi < 8; ++mi) {
        int rb = m0 + wm * 128 + mi * 16 + lq * 4;
#pragma unroll
        for (int nj = 0; nj < 4; ++nj) {
            int col = n0 + wn * 64 + nj * 16 + lrow;
            float bv = bias[col];
#pragma unroll
            for (int r = 0; r < 4; ++r)
                C[(size_t)(rb + r) * N + col] = acc[mi][nj][r] + bv;
        }
    }
}

// ---------------------------------------------------------------- launch ----
extern "C" void kernel_launch(void* const* d_in, const int* in_sizes, int n_in,
                              void* d_out, int out_size, void* d_ws, size_t ws_size,
                              hipStream_t stream) {
    const float* x    = (const float*)d_in[0];
    const float* w    = (const float*)d_in[1];
    const float* bias = (const float*)d_in[2];
    const float* cs   = (const float*)d_in[3];
    const float* th   = (const float*)d_in[4];
    const float* qs   = (const float*)d_in[5];
    const float* qzp  = (const float*)d_in[6];
    const int*   pr   = (const int*)d_in[7];
    float* out = (float*)d_out;

    char* ws = (char*)d_ws;
    double* ctab = (double*)ws;                                  // 64 KB
    double* stab = (double*)(ws + 65536);                        // 64 KB
    u16*    xb   = (u16*)(ws + 131072);                          // 64 MB
    u16*    wb   = (u16*)(ws + 131072 + (size_t)N_TOK * IN_F * 2);  // 32 MB

    hipLaunchKernelGGL(make_tabs, dim3((NSTAGE * NPAIRS + 255) / 256), dim3(256),
                       0, stream, th, ctab, stab);
    hipLaunchKernelGGL(build_w, dim3(OUT_F / ROWS_PW * 32 / 4), dim3(256),
                       0, stream, w, cs, qs, qzp, pr, ctab, stab, wb);
    hipLaunchKernelGGL(cast_x, dim3(N_TOK * IN_F / 4 / 256), dim3(256), 0, stream,
                       x, xb);
    hipLaunchKernelGGL(gemm_bt, dim3((N_TOK / 256) * (OUT_F / 256)), dim3(512),
                       0, stream, xb, wb, bias, out);
}